// Round 1
// baseline (316.085 us; speedup 1.0000x reference)
//
#include <hip/hip_runtime.h>

#define Tn 64
#define Bn 16384
#define Vn 29
#define Hn 20

typedef float f4 __attribute__((ext_vector_type(4)));

static __device__ __forceinline__ f4 ld4u(const float* p) {
  f4 v; __builtin_memcpy(&v, p, 16); return v;
}
static __device__ __forceinline__ void st4u(float* p, f4 v) {
  __builtin_memcpy(p, &v, 16);
}

#define LOG2E 1.4426950408889634f
#define LN2   0.6931471805599453f

static __device__ __forceinline__ float frcp(float x) {
#if __has_builtin(__builtin_amdgcn_rcpf)
  return __builtin_amdgcn_rcpf(x);
#else
  return 1.0f / x;
#endif
}
static __device__ __forceinline__ float fexp2(float x) {
#if __has_builtin(__builtin_amdgcn_exp2f)
  return __builtin_amdgcn_exp2f(x);
#else
  return exp2f(x);
#endif
}
static __device__ __forceinline__ float flog2(float x) {
#if __has_builtin(__builtin_amdgcn_logf)
  return __builtin_amdgcn_logf(x);
#else
  return log2f(x);
#endif
}
static __device__ __forceinline__ float ftanh(float x) {
  // tanh(x) = 1 - 2/(1+e^{2x}); saturates correctly at +/-inf
  float e = fexp2(x * (2.0f * LOG2E));
  return 1.0f - 2.0f * frcp(1.0f + e);
}

// lane swizzle (BitMode): src_lane = ((lane & and) | or) ^ xor, within 32-lane halves
#define SWZ(v, imm) __int_as_float(__builtin_amdgcn_ds_swizzle(__float_as_int(v), (imm)))
#define PAT(ow) (((ow) << 5) | 0x18)   /* broadcast from lane `ow` of each 8-group */

// ---------------------------------------------------------------------------
// K1: xi[t][b][h] = x[t,b,:] @ Wi[h,:] + bi[h] + bh[h] + (t==0)*img[b,h]
// 2 batch items per thread; Wi staged in LDS with rows padded to 32 floats.
// ---------------------------------------------------------------------------
__global__ __launch_bounds__(256, 3) void k_pre(
    const float* __restrict__ x, const float* __restrict__ img,
    const float* __restrict__ Wi, const float* __restrict__ bih,
    const float* __restrict__ bhh, float* __restrict__ xi)
{
  __shared__ f4 sW[Hn * 8];     // [20][32] floats, zero-padded cols 29..31
  __shared__ float sB[Hn];
  float* sWf = (float*)sW;
  const int tid = threadIdx.x;
  for (int i = tid; i < Hn * 32; i += 256) {
    int r = i >> 5, c = i & 31;
    sWf[i] = (c < Vn) ? Wi[r * Vn + c] : 0.0f;
  }
  if (tid < Hn) sB[tid] = bih[tid] + bhh[tid];
  __syncthreads();

  const int g  = blockIdx.x * 256 + tid;   // 0 .. T*B/2-1
  const int t  = g >> 13;                  // B/2 = 8192 pairs per t
  const int b0 = (g & 8191) << 1;

  const float* xr = x + ((size_t)t * Bn + b0) * Vn;
  f4 xa[8], xb[8];
#pragma unroll
  for (int q = 0; q < 7; ++q) {
    xa[q] = ld4u(xr + 4 * q);
    xb[q] = ld4u(xr + Vn + 4 * q);
  }
  xa[7] = f4{xr[28], 0.0f, 0.0f, 0.0f};
  xb[7] = f4{xr[Vn + 28], 0.0f, 0.0f, 0.0f};

  const bool first = (t == 0);
  const float* ia = img + (size_t)b0 * Hn;
  float* orow = xi + ((size_t)t * Bn + b0) * Hn;   // 80B rows -> 16B aligned

  float oa4[4], ob4[4];
#pragma unroll
  for (int h = 0; h < Hn; ++h) {
    float aa = sB[h], ab = sB[h];
#pragma unroll
    for (int q = 0; q < 8; ++q) {
      f4 w = sW[h * 8 + q];
      aa += w.x * xa[q].x + w.y * xa[q].y + w.z * xa[q].z + w.w * xa[q].w;
      ab += w.x * xb[q].x + w.y * xb[q].y + w.z * xb[q].z + w.w * xb[q].w;
    }
    if (first) { aa += ia[h]; ab += ia[Hn + h]; }
    oa4[h & 3] = aa; ob4[h & 3] = ab;
    if ((h & 3) == 3) {
      *(f4*)(orow + (h - 3))      = f4{oa4[0], oa4[1], oa4[2], oa4[3]};
      *(f4*)(orow + Hn + (h - 3)) = f4{ob4[0], ob4[1], ob4[2], ob4[3]};
    }
  }
}

// ---------------------------------------------------------------------------
// K2: recurrence + logits + log_softmax. 8 lanes per batch element.
// Lane j owns hidden rows {3j,3j+1,3j+2} (clamped; lane6 owns 18,19) and
// vocab rows {4j..4j+3} (clamped; lane7 owns 28 only). Weights in VGPRs.
// h_t broadcast across the 8-lane group with ds_swizzle.
// ---------------------------------------------------------------------------
__global__ __launch_bounds__(256, 2) void k_rnn(
    const float* __restrict__ xi, const float* __restrict__ Wh,
    const float* __restrict__ Who, const float* __restrict__ bho,
    float* __restrict__ out)
{
  const int gt = blockIdx.x * 256 + threadIdx.x;
  const int b = gt >> 3;
  const int j = gt & 7;

  // --- load per-lane weights into registers (rows 16B-aligned: 80B stride)
  float wh[3][Hn];
#pragma unroll
  for (int s = 0; s < 3; ++s) {
    int r = 3 * j + s; r = r > 19 ? 19 : r;
    const f4* wr = (const f4*)(Wh + r * Hn);
#pragma unroll
    for (int q = 0; q < 5; ++q) {
      f4 v = wr[q];
      wh[s][4*q] = v.x; wh[s][4*q+1] = v.y; wh[s][4*q+2] = v.z; wh[s][4*q+3] = v.w;
    }
  }
  float wo[4][Hn], bo[4];
#pragma unroll
  for (int rr = 0; rr < 4; ++rr) {
    int v = 4 * j + rr; int vc = v > 28 ? 28 : v;
    const f4* wr = (const f4*)(Who + vc * Hn);
#pragma unroll
    for (int q = 0; q < 5; ++q) {
      f4 w = wr[q];
      wo[rr][4*q] = w.x; wo[rr][4*q+1] = w.y; wo[rr][4*q+2] = w.z; wo[rr][4*q+3] = w.w;
    }
    bo[rr] = (v < Vn) ? bho[v] : -1e30f;   // mask invalid logits once, for free
  }

  int c0 = 3 * j;     c0 = c0 > 19 ? 19 : c0;
  int c1 = 3 * j + 1; c1 = c1 > 19 ? 19 : c1;
  int c2 = 3 * j + 2; c2 = c2 > 19 ? 19 : c2;

  const float* xp = xi + (size_t)b * Hn;
  float nx0 = xp[c0], nx1 = xp[c1], nx2 = xp[c2];

  float hbc[Hn];
#pragma unroll
  for (int k = 0; k < Hn; ++k) hbc[k] = 0.0f;   // h_{-1} = 0

  float* op = out + (size_t)b * Vn + 4 * j;
  const size_t xstep = (size_t)Bn * Hn;
  const size_t ostep = (size_t)Bn * Vn;

#pragma unroll 1
  for (int t = 0; t < Tn; ++t) {
    float a0 = nx0, a1 = nx1, a2 = nx2;
    xp += xstep;                       // prefetch t+1 (buffer has T+1 rows)
    nx0 = xp[c0]; nx1 = xp[c1]; nx2 = xp[c2];

#pragma unroll
    for (int k = 0; k < Hn; ++k) {
      float hk = hbc[k];
      a0 += hk * wh[0][k]; a1 += hk * wh[1][k]; a2 += hk * wh[2][k];
    }
    float h0 = ftanh(a0), h1 = ftanh(a1), h2 = ftanh(a2);

    // broadcast h_t: owner(k)=min(k/3,6), slot=k-3*owner
    hbc[0]  = SWZ(h0, PAT(0)); hbc[1]  = SWZ(h1, PAT(0)); hbc[2]  = SWZ(h2, PAT(0));
    hbc[3]  = SWZ(h0, PAT(1)); hbc[4]  = SWZ(h1, PAT(1)); hbc[5]  = SWZ(h2, PAT(1));
    hbc[6]  = SWZ(h0, PAT(2)); hbc[7]  = SWZ(h1, PAT(2)); hbc[8]  = SWZ(h2, PAT(2));
    hbc[9]  = SWZ(h0, PAT(3)); hbc[10] = SWZ(h1, PAT(3)); hbc[11] = SWZ(h2, PAT(3));
    hbc[12] = SWZ(h0, PAT(4)); hbc[13] = SWZ(h1, PAT(4)); hbc[14] = SWZ(h2, PAT(4));
    hbc[15] = SWZ(h0, PAT(5)); hbc[16] = SWZ(h1, PAT(5)); hbc[17] = SWZ(h2, PAT(5));
    hbc[18] = SWZ(h0, PAT(6)); hbc[19] = SWZ(h1, PAT(6));

    // logits (4 rows/lane)
    float l0 = bo[0], l1 = bo[1], l2 = bo[2], l3 = bo[3];
#pragma unroll
    for (int k = 0; k < Hn; ++k) {
      float hk = hbc[k];
      l0 += hk * wo[0][k]; l1 += hk * wo[1][k];
      l2 += hk * wo[2][k]; l3 += hk * wo[3][k];
    }

    // log-softmax over the 8-lane group (29 valid logits; invalid = -1e30)
    float m = fmaxf(fmaxf(l0, l1), fmaxf(l2, l3));
    m = fmaxf(m, SWZ(m, 0x041F));
    m = fmaxf(m, SWZ(m, 0x081F));
    m = fmaxf(m, SWZ(m, 0x101F));
    float e0 = fexp2((l0 - m) * LOG2E), e1 = fexp2((l1 - m) * LOG2E);
    float e2 = fexp2((l2 - m) * LOG2E), e3 = fexp2((l3 - m) * LOG2E);
    float s = e0 + e1 + e2 + e3;
    s += SWZ(s, 0x041F);
    s += SWZ(s, 0x081F);
    s += SWZ(s, 0x101F);
    float ls = m + flog2(s) * LN2;

    f4 o = f4{l0 - ls, l1 - ls, l2 - ls, l3 - ls};
    if (j < 7) st4u(op, o);
    else       op[0] = l0 - ls;
    op += ostep;
  }
}

extern "C" void kernel_launch(void* const* d_in, const int* in_sizes, int n_in,
                              void* d_out, int out_size, void* d_ws, size_t ws_size,
                              hipStream_t stream)
{
  const float* x   = (const float*)d_in[0];
  const float* img = (const float*)d_in[1];
  const float* Wi  = (const float*)d_in[2];
  const float* bi  = (const float*)d_in[3];
  const float* Wh  = (const float*)d_in[4];
  const float* bh  = (const float*)d_in[5];
  const float* Who = (const float*)d_in[6];
  const float* bho = (const float*)d_in[7];
  float* out = (float*)d_out;
  float* xi  = (float*)d_ws;   // needs (T+1)*B*H*4 = 85.2 MB of workspace

  // K1: T*B/2 threads (2 batch items each)
  k_pre<<<(Tn * Bn / 2) / 256, 256, 0, stream>>>(x, img, Wi, bi, bh, xi);
  // K2: 8 lanes per batch element
  k_rnn<<<(8 * Bn) / 256, 256, 0, stream>>>(xi, Wh, Who, bho, out);
}